// Round 3
// baseline (325.009 us; speedup 1.0000x reference)
//
#include <hip/hip_runtime.h>
#include <hip/hip_bf16.h>

namespace {

constexpr int BB = 8;
constexpr int NPTS = 2048;
constexpr int CC = 128;
constexpr int MM = BB * NPTS;   // 16384
constexpr int OO = 256;
constexpr int K1 = 160;         // 131 padded to multiple of 32
constexpr int KNNK = 16;
constexpr unsigned NBLK_GEMM = 256 * 4;  // gemm grid size (must all be resident)

typedef __attribute__((ext_vector_type(8))) short bf16x8;
typedef __attribute__((ext_vector_type(4))) float f32x4;

__device__ __forceinline__ unsigned short f2bf(float v) {
  unsigned u = __builtin_bit_cast(unsigned, v);
  u += 0x7FFFu + ((u >> 16) & 1u);
  return (unsigned short)(u >> 16);
}

__device__ __forceinline__ unsigned long long shflxor64(unsigned long long v, int m) {
  int lo = __shfl_xor((int)(unsigned)v, m, 64);
  int hi = __shfl_xor((int)(unsigned)(v >> 32), m, 64);
  return ((unsigned long long)(unsigned)hi << 32) | (unsigned)lo;
}

// Cheap xor-partner exchange: DPP for xor1/2, ds_swizzle for xor4/8/16, shfl for 32.
template <int J>
__device__ __forceinline__ unsigned long long partner64(unsigned long long v) {
  int lo = (int)(unsigned)v, hi = (int)(unsigned)(v >> 32);
  int plo, phi;
  if constexpr (J == 1) {        // quad_perm [1,0,3,2] = 0xB1
    plo = __builtin_amdgcn_mov_dpp(lo, 0xB1, 0xF, 0xF, true);
    phi = __builtin_amdgcn_mov_dpp(hi, 0xB1, 0xF, 0xF, true);
  } else if constexpr (J == 2) { // quad_perm [2,3,0,1] = 0x4E
    plo = __builtin_amdgcn_mov_dpp(lo, 0x4E, 0xF, 0xF, true);
    phi = __builtin_amdgcn_mov_dpp(hi, 0x4E, 0xF, 0xF, true);
  } else if constexpr (J == 4) {
    plo = __builtin_amdgcn_ds_swizzle(lo, 0x101F);
    phi = __builtin_amdgcn_ds_swizzle(hi, 0x101F);
  } else if constexpr (J == 8) {
    plo = __builtin_amdgcn_ds_swizzle(lo, 0x201F);
    phi = __builtin_amdgcn_ds_swizzle(hi, 0x201F);
  } else if constexpr (J == 16) {
    plo = __builtin_amdgcn_ds_swizzle(lo, 0x401F);
    phi = __builtin_amdgcn_ds_swizzle(hi, 0x401F);
  } else {
    plo = __shfl_xor(lo, 32, 64);
    phi = __shfl_xor(hi, 32, 64);
  }
  return ((unsigned long long)(unsigned)phi << 32) | (unsigned)plo;
}

__device__ __forceinline__ unsigned long long bitonic_sort64(unsigned long long key, int lane) {
#define BSTAGE(K, J)                                                        \
  {                                                                         \
    unsigned long long o = partner64<J>(key);                               \
    bool keepMin = (((lane & (K)) == 0) == ((lane & (J)) == 0));            \
    bool less = key < o;                                                    \
    key = (less == keepMin) ? key : o;                                      \
  }
  BSTAGE(2, 1)
  BSTAGE(4, 2) BSTAGE(4, 1)
  BSTAGE(8, 4) BSTAGE(8, 2) BSTAGE(8, 1)
  BSTAGE(16, 8) BSTAGE(16, 4) BSTAGE(16, 2) BSTAGE(16, 1)
  BSTAGE(32, 16) BSTAGE(32, 8) BSTAGE(32, 4) BSTAGE(32, 2) BSTAGE(32, 1)
  BSTAGE(64, 32) BSTAGE(64, 16) BSTAGE(64, 8) BSTAGE(64, 4) BSTAGE(64, 2) BSTAGE(64, 1)
#undef BSTAGE
  return key;
}

// W1 [131][256] f32 -> W1T bf16 [256][160]; W2 [256][256] -> W2T [256][256].
// Block 416 zeroes the stats block + barrier counters instead.
__global__ void prep_weights(const float* __restrict__ W1, const float* __restrict__ W2,
                             unsigned short* __restrict__ W1T, unsigned short* __restrict__ W2T,
                             double* __restrict__ stats) {
  if (blockIdx.x == 416) {
    for (int i = threadIdx.x; i < 1025; i += 256) stats[i] = 0.0;  // [1024] holds 2 u32 ctrs
    return;
  }
  int i = blockIdx.x * 256 + threadIdx.x;
  if (i < 256 * K1) {
    int n = i / K1, k = i % K1;
    float v = (k < 131) ? W1[k * 256 + n] : 0.f;
    W1T[i] = f2bf(v);
  } else {
    int j = i - 256 * K1;
    if (j < 256 * 256) {
      int n = j / 256, k = j % 256;
      W2T[j] = f2bf(W2[k * 256 + n]);
    }
  }
}

// Exact 16-NN, one wave per query. key = (f32_dist_bits << 11) | idx (unique ->
// lexicographic (d, idx) == jax.lax.top_k tie rule). Pass 1: compute all 32 keys
// per lane into REGISTERS, track per-lane min. Tkey = 16th smallest of the 64
// lane minima (safe bound; <= 481 survivors). Pass 2: ballot-compact from regs.
__global__ __launch_bounds__(256) void knn_kernel(const float* __restrict__ pos,
                                                  int* __restrict__ nn_idx) {
#pragma clang fp contract(off)
  __shared__ float4 pos4[NPTS];
  __shared__ unsigned long long sbuf[4][512];
  const int b = blockIdx.y;
  const int tid = threadIdx.x;
  const float* pb = pos + (size_t)b * NPTS * 3;
  for (int i = tid; i < NPTS; i += 256) {
    pos4[i] = make_float4(pb[3 * i], pb[3 * i + 1], pb[3 * i + 2], 0.f);
  }
  __syncthreads();
  const int lane = tid & 63;
  const int wid = tid >> 6;
  const int q = blockIdx.x * 4 + wid;  // query within batch
  const float4 qp = pos4[q];           // wave-uniform broadcast read

  unsigned long long keys[32];
  unsigned long long mink = ~0ull;
#pragma unroll
  for (int t = 0; t < 32; ++t) {
    const int j = lane + (t << 6);
    float4 p = pos4[j];
    float dx = qp.x - p.x;
    float dy = qp.y - p.y;
    float dz = qp.z - p.z;
    float d = ((dx * dx) + (dy * dy)) + (dz * dz);  // reference order, no fma
    unsigned long long key = ((unsigned long long)__float_as_uint(d) << 11) | (unsigned)j;
    keys[t] = key;
    mink = (key < mink) ? key : mink;
  }
  unsigned long long skey = bitonic_sort64(mink, lane);
  unsigned Tlo = (unsigned)__builtin_amdgcn_readlane((int)(unsigned)skey, 15);
  unsigned Thi = (unsigned)__builtin_amdgcn_readlane((int)(unsigned)(skey >> 32), 15);
  const unsigned long long Tkey = ((unsigned long long)Thi << 32) | Tlo;

  // Pass 2: compact survivors (key <= Tkey) into per-wave LDS buffer, from regs.
  unsigned long long* buf = sbuf[wid];
  int base = 0;
#pragma unroll
  for (int t = 0; t < 32; ++t) {
    unsigned long long key = keys[t];
    bool surv = key <= Tkey;
    unsigned long long mask = __ballot(surv);
    if (surv) {
      int off = __popcll(mask & ((1ull << lane) - 1ull));
      buf[base + off] = key;
    }
    base += (int)__popcll(mask);
  }

  int* out = nn_idx + ((size_t)b * NPTS + q) * KNNK;
  if (base <= 64) {
    unsigned long long key = (lane < base) ? buf[lane] : ~0ull;
    key = bitonic_sort64(key, lane);
    if (lane < 16) out[lane] = (int)(key & 2047ull);
  } else {
    // rare exact fallback: iterative wave-argmin extraction (base <= 481)
    unsigned long long mk[8];
#pragma unroll
    for (int j2 = 0; j2 < 8; ++j2) {
      int t2 = lane + (j2 << 6);
      mk[j2] = (t2 < base) ? buf[t2] : ~0ull;
    }
    for (int o = 0; o < 16; ++o) {
      unsigned long long m = mk[0];
#pragma unroll
      for (int j2 = 1; j2 < 8; ++j2) m = (mk[j2] < m) ? mk[j2] : m;
#pragma unroll
      for (int off = 32; off > 0; off >>= 1) {
        unsigned long long o2 = shflxor64(m, off);
        m = (o2 < m) ? o2 : m;
      }
      if (lane == 0) out[o] = (int)(m & 2047ull);
#pragma unroll
      for (int j2 = 0; j2 < 8; ++j2) mk[j2] = (mk[j2] == m) ? ~0ull : mk[j2];
    }
  }
}

// avg[p][0:128] = mean_k x[b, idx[k], c]; [128:131] = mean pos; [131:160]=0  (bf16)
__global__ __launch_bounds__(128) void gather_avg(const float* __restrict__ x,
                                                  const float* __restrict__ pos,
                                                  const int* __restrict__ nn_idx,
                                                  unsigned short* __restrict__ avg) {
  __shared__ int sidx[16];
  const int p = blockIdx.x;
  const int b = p >> 11;
  const int tid = threadIdx.x;
  if (tid < 16) sidx[tid] = nn_idx[(size_t)p * KNNK + tid];
  __syncthreads();
  const float* xb = x + (size_t)b * NPTS * CC;
  float sacc = 0.f;
#pragma unroll
  for (int k = 0; k < 16; ++k) sacc += xb[(size_t)sidx[k] * CC + tid];
  avg[(size_t)p * K1 + tid] = f2bf(sacc * 0.0625f);
  if (tid < 32) {
    float v = 0.f;
    if (tid < 3) {
      const float* pb = pos + (size_t)b * NPTS * 3;
#pragma unroll
      for (int k = 0; k < 16; ++k) v += pb[sidx[k] * 3 + tid];
      v *= 0.0625f;
    }
    avg[(size_t)p * K1 + 128 + tid] = f2bf(v);
  }
}

// Fused GEMM + train-BN (+ReLU+bf16 for FIRST) with hand-rolled grid barrier.
// Residency guarantee: 1024 blocks, <=128 VGPR (launch_bounds), 15.4KB LDS
// -> exactly 4 blocks/CU on 256 CUs, so all blocks run concurrently.
template <bool FIRST>
__global__ __launch_bounds__(256, 4) void gemm_fused(
    const unsigned short* __restrict__ A, const unsigned short* __restrict__ BT,
    const float* __restrict__ bias, const float* __restrict__ gamma,
    const float* __restrict__ beta, double* __restrict__ dsum,
    double* __restrict__ dsumsq, unsigned* __restrict__ ctr,
    void* __restrict__ outp, int Kp) {
  __shared__ __align__(16) unsigned short As[64][56];
  __shared__ __align__(16) unsigned short Bs[64][56];
  __shared__ float sSum[64], sSq[64], sScale[64], sShift[64];
  const int tid = threadIdx.x;
  if (tid < 64) { sSum[tid] = 0.f; sSq[tid] = 0.f; }
  const int m0 = blockIdx.x * 64;
  const int n0 = blockIdx.y * 64;
  const int w = tid >> 6, lane = tid & 63;
  const int wr = w >> 1, wc = w & 1;
  const int l15 = lane & 15;
  const int g = lane >> 4;
  const int kk = g * 8;
  f32x4 acc[2][2] = {};
  const int sr = tid >> 2;
  const int sk = (tid & 3) * 8;
  const unsigned short* Aptr = A + (size_t)(m0 + sr) * Kp + sk;
  const unsigned short* Bptr = BT + (size_t)(n0 + sr) * Kp + sk;
  for (int k0 = 0; k0 < Kp; k0 += 32) {
    *(int4*)(&As[sr][sk]) = *(const int4*)(Aptr + k0);
    *(int4*)(&Bs[sr][sk]) = *(const int4*)(Bptr + k0);
    __syncthreads();
    bf16x8 a0  = *(const bf16x8*)(&As[wr * 32 + l15][kk]);
    bf16x8 a1  = *(const bf16x8*)(&As[wr * 32 + 16 + l15][kk]);
    bf16x8 b0  = *(const bf16x8*)(&Bs[wc * 32 + l15][kk]);
    bf16x8 b1v = *(const bf16x8*)(&Bs[wc * 32 + 16 + l15][kk]);
    acc[0][0] = __builtin_amdgcn_mfma_f32_16x16x32_bf16(a0, b0,  acc[0][0], 0, 0, 0);
    acc[0][1] = __builtin_amdgcn_mfma_f32_16x16x32_bf16(a0, b1v, acc[0][1], 0, 0, 0);
    acc[1][0] = __builtin_amdgcn_mfma_f32_16x16x32_bf16(a1, b0,  acc[1][0], 0, 0, 0);
    acc[1][1] = __builtin_amdgcn_mfma_f32_16x16x32_bf16(a1, b1v, acc[1][1], 0, 0, 0);
    __syncthreads();
  }

  // v = acc + bias (the pre-BN activations, identical to old pre1/pre2 values)
  float v[2][2][4];
  float s[2] = {0.f, 0.f}, q2[2] = {0.f, 0.f};
#pragma unroll
  for (int fc = 0; fc < 2; ++fc) {
    float bv = bias[n0 + wc * 32 + fc * 16 + l15];
#pragma unroll
    for (int fr = 0; fr < 2; ++fr)
#pragma unroll
      for (int r = 0; r < 4; ++r) {
        float x = acc[fr][fc][r] + bv;
        v[fr][fc][r] = x;
        s[fc] += x;
        q2[fc] = fmaf(x, x, q2[fc]);
      }
  }
  // reduce over the 4 row-groups (lanes differing in bits 4,5)
#pragma unroll
  for (int fc = 0; fc < 2; ++fc) {
    s[fc] += __shfl_xor(s[fc], 16, 64);
    s[fc] += __shfl_xor(s[fc], 32, 64);
    q2[fc] += __shfl_xor(q2[fc], 16, 64);
    q2[fc] += __shfl_xor(q2[fc], 32, 64);
  }
  if (lane < 16) {
#pragma unroll
    for (int fc = 0; fc < 2; ++fc) {
      atomicAdd(&sSum[wc * 32 + fc * 16 + lane], s[fc]);   // 2 adds/addr: order-exact
      atomicAdd(&sSq[wc * 32 + fc * 16 + lane], q2[fc]);
    }
  }
  __syncthreads();
  if (tid < 64) {
    atomicAdd(&dsum[n0 + tid], (double)sSum[tid]);
    atomicAdd(&dsumsq[n0 + tid], (double)sSq[tid]);
  }
  // ---- grid barrier (all 1024 blocks resident by construction) ----
  __syncthreads();   // drains the global atomics (waitcnt before barrier)
  __threadfence();
  if (tid == 0) {
    __hip_atomic_fetch_add(ctr, 1u, __ATOMIC_ACQ_REL, __HIP_MEMORY_SCOPE_AGENT);
    while (__hip_atomic_load(ctr, __ATOMIC_ACQUIRE, __HIP_MEMORY_SCOPE_AGENT) != NBLK_GEMM)
      __builtin_amdgcn_s_sleep(2);
  }
  __syncthreads();
  // ---- finalize BN params for this block's 64 columns ----
  if (tid < 64) {
    int c = n0 + tid;
    double mu = dsum[c] * (1.0 / 16384.0);
    double var = dsumsq[c] * (1.0 / 16384.0) - mu * mu;
    float sc = (float)((double)gamma[c] / sqrt(var + 1e-5));
    float sh = beta[c] - (float)mu * sc;
    sScale[tid] = sc;
    sShift[tid] = sh;
  }
  __syncthreads();
  // ---- apply BN (+ReLU/bf16) straight from registers ----
#pragma unroll
  for (int fc = 0; fc < 2; ++fc) {
    int cl = wc * 32 + fc * 16 + l15;
    float sc = sScale[cl], sh = sShift[cl];
#pragma unroll
    for (int fr = 0; fr < 2; ++fr)
#pragma unroll
      for (int r = 0; r < 4; ++r) {
        int row = m0 + wr * 32 + fr * 16 + g * 4 + r;
        float o = fmaf(v[fr][fc][r], sc, sh);
        if constexpr (FIRST) {
          ((unsigned short*)outp)[(size_t)row * OO + n0 + cl] = f2bf(fmaxf(o, 0.f));
        } else {
          ((float*)outp)[(size_t)row * OO + n0 + cl] = o;
        }
      }
  }
}

}  // namespace

extern "C" void kernel_launch(void* const* d_in, const int* in_sizes, int n_in,
                              void* d_out, int out_size, void* d_ws, size_t ws_size,
                              hipStream_t stream) {
  const float* x   = (const float*)d_in[0];
  const float* pos = (const float*)d_in[1];
  const float* W1  = (const float*)d_in[2];
  const float* b1  = (const float*)d_in[3];
  const float* g1  = (const float*)d_in[4];
  const float* be1 = (const float*)d_in[5];
  const float* W2  = (const float*)d_in[6];
  const float* b2  = (const float*)d_in[7];
  const float* g2  = (const float*)d_in[8];
  const float* be2 = (const float*)d_in[9];

  char* ws = (char*)d_ws;
  double* stats        = (double*)(ws + 0);              // 1024 doubles + ctrs
  unsigned* ctr        = (unsigned*)(ws + 8192);         // 2 barrier counters
  int* nn_idx          = (int*)(ws + 12288);             // 16384*16 int
  unsigned short* avg  = (unsigned short*)(ws + 1060864);    // 16384*160 bf16
  unsigned short* W1T  = (unsigned short*)(ws + 6303744);    // 256*160 bf16
  unsigned short* W2T  = (unsigned short*)(ws + 6385664);    // 256*256 bf16
  unsigned short* hbuf = (unsigned short*)(ws + 6516736);    // 16384*256 bf16

  prep_weights<<<417, 256, 0, stream>>>(W1, W2, W1T, W2T, stats);
  knn_kernel<<<dim3(NPTS / 4, BB), 256, 0, stream>>>(pos, nn_idx);
  gather_avg<<<MM, 128, 0, stream>>>(x, pos, nn_idx, avg);
  gemm_fused<true><<<dim3(MM / 64, OO / 64), 256, 0, stream>>>(
      avg, W1T, b1, g1, be1, stats, stats + 256, ctr, hbuf, K1);
  gemm_fused<false><<<dim3(MM / 64, OO / 64), 256, 0, stream>>>(
      hbuf, W2T, b2, g2, be2, stats + 512, stats + 768, ctr + 1, d_out, OO);
}

// Round 4
// 98.990 us; speedup vs baseline: 3.2833x; 3.2833x over previous
//
#include <hip/hip_runtime.h>
#include <hip/hip_bf16.h>

namespace {

constexpr int BB = 8;
constexpr int NPTS = 2048;
constexpr int CC = 128;
constexpr int MM = BB * NPTS;   // 16384
constexpr int OO = 256;
constexpr int K1 = 160;         // 131 padded to multiple of 32
constexpr int KNNK = 16;

typedef __attribute__((ext_vector_type(8))) short bf16x8;
typedef __attribute__((ext_vector_type(8))) unsigned short u16x8;
typedef __attribute__((ext_vector_type(4))) float f32x4;

__device__ __forceinline__ unsigned short f2bf(float v) {
  unsigned u = __builtin_bit_cast(unsigned, v);
  u += 0x7FFFu + ((u >> 16) & 1u);
  return (unsigned short)(u >> 16);
}

__device__ __forceinline__ float bf2f(unsigned short s) {
  unsigned u = (unsigned)s << 16;
  return __builtin_bit_cast(float, u);
}

__device__ __forceinline__ unsigned long long shflxor64(unsigned long long v, int m) {
  int lo = __shfl_xor((int)(unsigned)v, m, 64);
  int hi = __shfl_xor((int)(unsigned)(v >> 32), m, 64);
  return ((unsigned long long)(unsigned)hi << 32) | (unsigned)lo;
}

// Cheap xor-partner exchange: DPP for xor1/2, ds_swizzle for xor4/8/16, shfl for 32.
template <int J>
__device__ __forceinline__ unsigned long long partner64(unsigned long long v) {
  int lo = (int)(unsigned)v, hi = (int)(unsigned)(v >> 32);
  int plo, phi;
  if constexpr (J == 1) {        // quad_perm [1,0,3,2] = 0xB1
    plo = __builtin_amdgcn_mov_dpp(lo, 0xB1, 0xF, 0xF, true);
    phi = __builtin_amdgcn_mov_dpp(hi, 0xB1, 0xF, 0xF, true);
  } else if constexpr (J == 2) { // quad_perm [2,3,0,1] = 0x4E
    plo = __builtin_amdgcn_mov_dpp(lo, 0x4E, 0xF, 0xF, true);
    phi = __builtin_amdgcn_mov_dpp(hi, 0x4E, 0xF, 0xF, true);
  } else if constexpr (J == 4) {
    plo = __builtin_amdgcn_ds_swizzle(lo, 0x101F);
    phi = __builtin_amdgcn_ds_swizzle(hi, 0x101F);
  } else if constexpr (J == 8) {
    plo = __builtin_amdgcn_ds_swizzle(lo, 0x201F);
    phi = __builtin_amdgcn_ds_swizzle(hi, 0x201F);
  } else if constexpr (J == 16) {
    plo = __builtin_amdgcn_ds_swizzle(lo, 0x401F);
    phi = __builtin_amdgcn_ds_swizzle(hi, 0x401F);
  } else {
    plo = __shfl_xor(lo, 32, 64);
    phi = __shfl_xor(hi, 32, 64);
  }
  return ((unsigned long long)(unsigned)phi << 32) | (unsigned)plo;
}

__device__ __forceinline__ unsigned long long bitonic_sort64(unsigned long long key, int lane) {
#define BSTAGE(K, J)                                                        \
  {                                                                         \
    unsigned long long o = partner64<J>(key);                               \
    bool keepMin = (((lane & (K)) == 0) == ((lane & (J)) == 0));            \
    bool less = key < o;                                                    \
    key = (less == keepMin) ? key : o;                                      \
  }
  BSTAGE(2, 1)
  BSTAGE(4, 2) BSTAGE(4, 1)
  BSTAGE(8, 4) BSTAGE(8, 2) BSTAGE(8, 1)
  BSTAGE(16, 8) BSTAGE(16, 4) BSTAGE(16, 2) BSTAGE(16, 1)
  BSTAGE(32, 16) BSTAGE(32, 8) BSTAGE(32, 4) BSTAGE(32, 2) BSTAGE(32, 1)
  BSTAGE(64, 32) BSTAGE(64, 16) BSTAGE(64, 8) BSTAGE(64, 4) BSTAGE(64, 2) BSTAGE(64, 1)
#undef BSTAGE
  return key;
}

// W1 [131][256] f32 -> W1T bf16 [256][160]; W2 [256][256] -> W2T [256][256].
// Block 416 zeroes the 1024-double stats block instead.
__global__ void prep_weights(const float* __restrict__ W1, const float* __restrict__ W2,
                             unsigned short* __restrict__ W1T, unsigned short* __restrict__ W2T,
                             double* __restrict__ stats) {
  if (blockIdx.x == 416) {
    for (int i = threadIdx.x; i < 1024; i += 256) stats[i] = 0.0;
    return;
  }
  int i = blockIdx.x * 256 + threadIdx.x;
  if (i < 256 * K1) {
    int n = i / K1, k = i % K1;
    float v = (k < 131) ? W1[k * 256 + n] : 0.f;
    W1T[i] = f2bf(v);
  } else {
    int j = i - 256 * K1;
    if (j < 256 * 256) {
      int n = j / 256, k = j % 256;
      W2T[j] = f2bf(W2[k * 256 + n]);
    }
  }
}

// Exact 16-NN, one wave per query. key = (f32_dist_bits << 11) | idx (unique ->
// lexicographic (d, idx) == jax.lax.top_k tie rule). Pass 1: compute all 32 keys
// per lane into REGISTERS, track per-lane min. Tkey = 16th smallest of the 64
// lane minima (safe bound; <= 481 survivors). Pass 2: ballot-compact from regs.
__global__ __launch_bounds__(256) void knn_kernel(const float* __restrict__ pos,
                                                  int* __restrict__ nn_idx) {
#pragma clang fp contract(off)
  __shared__ float4 pos4[NPTS];
  __shared__ unsigned long long sbuf[4][512];
  const int b = blockIdx.y;
  const int tid = threadIdx.x;
  const float* pb = pos + (size_t)b * NPTS * 3;
  for (int i = tid; i < NPTS; i += 256) {
    pos4[i] = make_float4(pb[3 * i], pb[3 * i + 1], pb[3 * i + 2], 0.f);
  }
  __syncthreads();
  const int lane = tid & 63;
  const int wid = tid >> 6;
  const int q = blockIdx.x * 4 + wid;  // query within batch
  const float4 qp = pos4[q];           // wave-uniform broadcast read

  unsigned long long keys[32];
  unsigned long long mink = ~0ull;
#pragma unroll
  for (int t = 0; t < 32; ++t) {
    const int j = lane + (t << 6);
    float4 p = pos4[j];
    float dx = qp.x - p.x;
    float dy = qp.y - p.y;
    float dz = qp.z - p.z;
    float d = ((dx * dx) + (dy * dy)) + (dz * dz);  // reference order, no fma
    unsigned long long key = ((unsigned long long)__float_as_uint(d) << 11) | (unsigned)j;
    keys[t] = key;
    mink = (key < mink) ? key : mink;
  }
  unsigned long long skey = bitonic_sort64(mink, lane);
  unsigned Tlo = (unsigned)__builtin_amdgcn_readlane((int)(unsigned)skey, 15);
  unsigned Thi = (unsigned)__builtin_amdgcn_readlane((int)(unsigned)(skey >> 32), 15);
  const unsigned long long Tkey = ((unsigned long long)Thi << 32) | Tlo;

  // Pass 2: compact survivors (key <= Tkey) into per-wave LDS buffer, from regs.
  unsigned long long* buf = sbuf[wid];
  int base = 0;
#pragma unroll
  for (int t = 0; t < 32; ++t) {
    unsigned long long key = keys[t];
    bool surv = key <= Tkey;
    unsigned long long mask = __ballot(surv);
    if (surv) {
      int off = __popcll(mask & ((1ull << lane) - 1ull));
      buf[base + off] = key;
    }
    base += (int)__popcll(mask);
  }

  int* out = nn_idx + ((size_t)b * NPTS + q) * KNNK;
  if (base <= 64) {
    unsigned long long key = (lane < base) ? buf[lane] : ~0ull;
    key = bitonic_sort64(key, lane);
    if (lane < 16) out[lane] = (int)(key & 2047ull);
  } else {
    // rare exact fallback: iterative wave-argmin extraction (base <= 481)
    unsigned long long mk[8];
#pragma unroll
    for (int j2 = 0; j2 < 8; ++j2) {
      int t2 = lane + (j2 << 6);
      mk[j2] = (t2 < base) ? buf[t2] : ~0ull;
    }
    for (int o = 0; o < 16; ++o) {
      unsigned long long m = mk[0];
#pragma unroll
      for (int j2 = 1; j2 < 8; ++j2) m = (mk[j2] < m) ? mk[j2] : m;
#pragma unroll
      for (int off = 32; off > 0; off >>= 1) {
        unsigned long long o2 = shflxor64(m, off);
        m = (o2 < m) ? o2 : m;
      }
      if (lane == 0) out[o] = (int)(m & 2047ull);
#pragma unroll
      for (int j2 = 0; j2 < 8; ++j2) mk[j2] = (mk[j2] == m) ? ~0ull : mk[j2];
    }
  }
}

// avg[p][0:128] = mean_k x[b, idx[k], c]; [128:131] = mean pos; [131:160]=0  (bf16)
__global__ __launch_bounds__(128) void gather_avg(const float* __restrict__ x,
                                                  const float* __restrict__ pos,
                                                  const int* __restrict__ nn_idx,
                                                  unsigned short* __restrict__ avg) {
  __shared__ int sidx[16];
  const int p = blockIdx.x;
  const int b = p >> 11;
  const int tid = threadIdx.x;
  if (tid < 16) sidx[tid] = nn_idx[(size_t)p * KNNK + tid];
  __syncthreads();
  const float* xb = x + (size_t)b * NPTS * CC;
  float sacc = 0.f;
#pragma unroll
  for (int k = 0; k < 16; ++k) sacc += xb[(size_t)sidx[k] * CC + tid];
  avg[(size_t)p * K1 + tid] = f2bf(sacc * 0.0625f);
  if (tid < 32) {
    float v = 0.f;
    if (tid < 3) {
      const float* pb = pos + (size_t)b * NPTS * 3;
#pragma unroll
      for (int k = 0; k < 16; ++k) v += pb[sidx[k] * 3 + tid];
      v *= 0.0625f;
    }
    avg[(size_t)p * K1 + 128 + tid] = f2bf(v);
  }
}

// GEMM + bias; accumulates per-column sum/sumsq into global doubles (block
// partials via shuffle + LDS float atomics, one double atomic per col/block);
// writes pre-activations as bf16. No grid sync.
__global__ __launch_bounds__(256) void gemm_stats(
    const unsigned short* __restrict__ A, const unsigned short* __restrict__ BT,
    const float* __restrict__ bias, double* __restrict__ dsum,
    double* __restrict__ dsumsq, unsigned short* __restrict__ pre, int Kp) {
  __shared__ __align__(16) unsigned short As[64][56];
  __shared__ __align__(16) unsigned short Bs[64][56];
  __shared__ float sSum[64], sSq[64];
  const int tid = threadIdx.x;
  if (tid < 64) { sSum[tid] = 0.f; sSq[tid] = 0.f; }
  const int m0 = blockIdx.x * 64;
  const int n0 = blockIdx.y * 64;
  const int w = tid >> 6, lane = tid & 63;
  const int wr = w >> 1, wc = w & 1;
  const int l15 = lane & 15;
  const int g = lane >> 4;
  const int kk = g * 8;
  f32x4 acc[2][2] = {};
  const int sr = tid >> 2;
  const int sk = (tid & 3) * 8;
  const unsigned short* Aptr = A + (size_t)(m0 + sr) * Kp + sk;
  const unsigned short* Bptr = BT + (size_t)(n0 + sr) * Kp + sk;
  for (int k0 = 0; k0 < Kp; k0 += 32) {
    *(int4*)(&As[sr][sk]) = *(const int4*)(Aptr + k0);
    *(int4*)(&Bs[sr][sk]) = *(const int4*)(Bptr + k0);
    __syncthreads();
    bf16x8 a0  = *(const bf16x8*)(&As[wr * 32 + l15][kk]);
    bf16x8 a1  = *(const bf16x8*)(&As[wr * 32 + 16 + l15][kk]);
    bf16x8 b0  = *(const bf16x8*)(&Bs[wc * 32 + l15][kk]);
    bf16x8 b1v = *(const bf16x8*)(&Bs[wc * 32 + 16 + l15][kk]);
    acc[0][0] = __builtin_amdgcn_mfma_f32_16x16x32_bf16(a0, b0,  acc[0][0], 0, 0, 0);
    acc[0][1] = __builtin_amdgcn_mfma_f32_16x16x32_bf16(a0, b1v, acc[0][1], 0, 0, 0);
    acc[1][0] = __builtin_amdgcn_mfma_f32_16x16x32_bf16(a1, b0,  acc[1][0], 0, 0, 0);
    acc[1][1] = __builtin_amdgcn_mfma_f32_16x16x32_bf16(a1, b1v, acc[1][1], 0, 0, 0);
    __syncthreads();
  }

  float s[2] = {0.f, 0.f}, q2[2] = {0.f, 0.f};
  unsigned short vb[2][2][4];
#pragma unroll
  for (int fc = 0; fc < 2; ++fc) {
    float bv = bias[n0 + wc * 32 + fc * 16 + l15];
#pragma unroll
    for (int fr = 0; fr < 2; ++fr)
#pragma unroll
      for (int r = 0; r < 4; ++r) {
        float xv = acc[fr][fc][r] + bv;
        unsigned short h = f2bf(xv);
        vb[fr][fc][r] = h;
        float xq = bf2f(h);          // stats from the stored bf16 values
        s[fc] += xq;
        q2[fc] = fmaf(xq, xq, q2[fc]);
      }
  }
#pragma unroll
  for (int fc = 0; fc < 2; ++fc) {
    s[fc] += __shfl_xor(s[fc], 16, 64);
    s[fc] += __shfl_xor(s[fc], 32, 64);
    q2[fc] += __shfl_xor(q2[fc], 16, 64);
    q2[fc] += __shfl_xor(q2[fc], 32, 64);
  }
  if (lane < 16) {
#pragma unroll
    for (int fc = 0; fc < 2; ++fc) {
      atomicAdd(&sSum[wc * 32 + fc * 16 + lane], s[fc]);
      atomicAdd(&sSq[wc * 32 + fc * 16 + lane], q2[fc]);
    }
  }
  // write pre-activation bf16 while the LDS reduction settles
#pragma unroll
  for (int fc = 0; fc < 2; ++fc) {
    int col = n0 + wc * 32 + fc * 16 + l15;
#pragma unroll
    for (int fr = 0; fr < 2; ++fr)
#pragma unroll
      for (int r = 0; r < 4; ++r) {
        int row = m0 + wr * 32 + fr * 16 + g * 4 + r;
        pre[(size_t)row * OO + col] = vb[fr][fc][r];
      }
  }
  __syncthreads();
  if (tid < 64) {
    atomicAdd(&dsum[n0 + tid], (double)sSum[tid]);
    atomicAdd(&dsumsq[n0 + tid], (double)sSq[tid]);
  }
}

// Streams pre (bf16 [MM][256]) -> BN(+ReLU). Each block derives scale/shift
// from the global double stats itself (no separate finalize kernel).
template <bool RELU>
__global__ __launch_bounds__(256) void bn_apply(const unsigned short* __restrict__ pre,
                                                const double* __restrict__ dsum,
                                                const double* __restrict__ dsumsq,
                                                const float* __restrict__ gamma,
                                                const float* __restrict__ beta,
                                                void* __restrict__ outp) {
  __shared__ float sSc[256], sSh[256];
  const int tid = threadIdx.x;
  {
    double mu = dsum[tid] * (1.0 / 16384.0);
    double var = dsumsq[tid] * (1.0 / 16384.0) - mu * mu;
    float sc = (float)((double)gamma[tid] / sqrt(var + 1e-5));
    sSc[tid] = sc;
    sSh[tid] = beta[tid] - (float)mu * sc;
  }
  __syncthreads();
  const int cg = (tid & 31) * 8;
  float sc[8], sh[8];
#pragma unroll
  for (int j = 0; j < 8; ++j) { sc[j] = sSc[cg + j]; sh[j] = sSh[cg + j]; }
  const int r0 = blockIdx.x * 32 + (tid >> 5);
#pragma unroll
  for (int it = 0; it < 4; ++it) {
    const int row = r0 + it * 8;
    u16x8 v = *(const u16x8*)(pre + (size_t)row * OO + cg);
    if constexpr (RELU) {
      u16x8 o;
#pragma unroll
      for (int j = 0; j < 8; ++j)
        o[j] = f2bf(fmaxf(fmaf(bf2f(v[j]), sc[j], sh[j]), 0.f));
      *(u16x8*)((unsigned short*)outp + (size_t)row * OO + cg) = o;
    } else {
      float4 o0, o1;
      o0.x = fmaf(bf2f(v[0]), sc[0], sh[0]);
      o0.y = fmaf(bf2f(v[1]), sc[1], sh[1]);
      o0.z = fmaf(bf2f(v[2]), sc[2], sh[2]);
      o0.w = fmaf(bf2f(v[3]), sc[3], sh[3]);
      o1.x = fmaf(bf2f(v[4]), sc[4], sh[4]);
      o1.y = fmaf(bf2f(v[5]), sc[5], sh[5]);
      o1.z = fmaf(bf2f(v[6]), sc[6], sh[6]);
      o1.w = fmaf(bf2f(v[7]), sc[7], sh[7]);
      float* op = (float*)outp + (size_t)row * OO + cg;
      *(float4*)op = o0;
      *(float4*)(op + 4) = o1;
    }
  }
}

}  // namespace

extern "C" void kernel_launch(void* const* d_in, const int* in_sizes, int n_in,
                              void* d_out, int out_size, void* d_ws, size_t ws_size,
                              hipStream_t stream) {
  const float* x   = (const float*)d_in[0];
  const float* pos = (const float*)d_in[1];
  const float* W1  = (const float*)d_in[2];
  const float* b1  = (const float*)d_in[3];
  const float* g1  = (const float*)d_in[4];
  const float* be1 = (const float*)d_in[5];
  const float* W2  = (const float*)d_in[6];
  const float* b2  = (const float*)d_in[7];
  const float* g2  = (const float*)d_in[8];
  const float* be2 = (const float*)d_in[9];

  char* ws = (char*)d_ws;
  double* stats        = (double*)(ws + 0);                  // 1024 doubles
  int* nn_idx          = (int*)(ws + 12288);                 // 16384*16 int
  unsigned short* avg  = (unsigned short*)(ws + 1060864);    // 16384*160 bf16
  unsigned short* W1T  = (unsigned short*)(ws + 6303744);    // 256*160 bf16
  unsigned short* W2T  = (unsigned short*)(ws + 6385664);    // 256*256 bf16
  unsigned short* hbuf = (unsigned short*)(ws + 6516736);    // 16384*256 bf16
  unsigned short* pre1 = (unsigned short*)(ws + 14905344);   // 16384*256 bf16
  unsigned short* pre2 = (unsigned short*)(ws + 23293952);   // 16384*256 bf16

  prep_weights<<<417, 256, 0, stream>>>(W1, W2, W1T, W2T, stats);
  knn_kernel<<<dim3(NPTS / 4, BB), 256, 0, stream>>>(pos, nn_idx);
  gather_avg<<<MM, 128, 0, stream>>>(x, pos, nn_idx, avg);
  gemm_stats<<<dim3(MM / 64, OO / 64), 256, 0, stream>>>(
      avg, W1T, b1, stats, stats + 256, pre1, K1);
  bn_apply<true><<<MM / 32, 256, 0, stream>>>(pre1, stats, stats + 256, g1, be1, hbuf);
  gemm_stats<<<dim3(MM / 64, OO / 64), 256, 0, stream>>>(
      hbuf, W2T, b2, stats + 512, stats + 768, pre2, OO);
  bn_apply<false><<<MM / 32, 256, 0, stream>>>(pre2, stats + 512, stats + 768, g2, be2, d_out);
}

// Round 5
// 92.848 us; speedup vs baseline: 3.5004x; 1.0661x over previous
//
#include <hip/hip_runtime.h>
#include <hip/hip_bf16.h>

namespace {

constexpr int BB = 8;
constexpr int NPTS = 2048;
constexpr int CC = 128;
constexpr int MM = BB * NPTS;   // 16384
constexpr int OO = 256;
constexpr int K1 = 160;         // 131 padded to multiple of 32
constexpr int KNNK = 16;

typedef __attribute__((ext_vector_type(8))) short bf16x8;
typedef __attribute__((ext_vector_type(8))) unsigned short u16x8;
typedef __attribute__((ext_vector_type(4))) float f32x4;

__device__ __forceinline__ unsigned short f2bf(float v) {
  unsigned u = __builtin_bit_cast(unsigned, v);
  u += 0x7FFFu + ((u >> 16) & 1u);
  return (unsigned short)(u >> 16);
}

__device__ __forceinline__ float bf2f(unsigned short s) {
  unsigned u = (unsigned)s << 16;
  return __builtin_bit_cast(float, u);
}

__device__ __forceinline__ unsigned long long shflxor64(unsigned long long v, int m) {
  int lo = __shfl_xor((int)(unsigned)v, m, 64);
  int hi = __shfl_xor((int)(unsigned)(v >> 32), m, 64);
  return ((unsigned long long)(unsigned)hi << 32) | (unsigned)lo;
}

// Cheap xor-partner exchange: DPP for xor1/2, ds_swizzle for xor4/8/16, shfl for 32.
template <int J>
__device__ __forceinline__ unsigned long long partner64(unsigned long long v) {
  int lo = (int)(unsigned)v, hi = (int)(unsigned)(v >> 32);
  int plo, phi;
  if constexpr (J == 1) {        // quad_perm [1,0,3,2] = 0xB1
    plo = __builtin_amdgcn_mov_dpp(lo, 0xB1, 0xF, 0xF, true);
    phi = __builtin_amdgcn_mov_dpp(hi, 0xB1, 0xF, 0xF, true);
  } else if constexpr (J == 2) { // quad_perm [2,3,0,1] = 0x4E
    plo = __builtin_amdgcn_mov_dpp(lo, 0x4E, 0xF, 0xF, true);
    phi = __builtin_amdgcn_mov_dpp(hi, 0x4E, 0xF, 0xF, true);
  } else if constexpr (J == 4) {
    plo = __builtin_amdgcn_ds_swizzle(lo, 0x101F);
    phi = __builtin_amdgcn_ds_swizzle(hi, 0x101F);
  } else if constexpr (J == 8) {
    plo = __builtin_amdgcn_ds_swizzle(lo, 0x201F);
    phi = __builtin_amdgcn_ds_swizzle(hi, 0x201F);
  } else if constexpr (J == 16) {
    plo = __builtin_amdgcn_ds_swizzle(lo, 0x401F);
    phi = __builtin_amdgcn_ds_swizzle(hi, 0x401F);
  } else {
    plo = __shfl_xor(lo, 32, 64);
    phi = __shfl_xor(hi, 32, 64);
  }
  return ((unsigned long long)(unsigned)phi << 32) | (unsigned)plo;
}

__device__ __forceinline__ unsigned long long bitonic_sort64(unsigned long long key, int lane) {
#define BSTAGE(K, J)                                                        \
  {                                                                         \
    unsigned long long o = partner64<J>(key);                               \
    bool keepMin = (((lane & (K)) == 0) == ((lane & (J)) == 0));            \
    bool less = key < o;                                                    \
    key = (less == keepMin) ? key : o;                                      \
  }
  BSTAGE(2, 1)
  BSTAGE(4, 2) BSTAGE(4, 1)
  BSTAGE(8, 4) BSTAGE(8, 2) BSTAGE(8, 1)
  BSTAGE(16, 8) BSTAGE(16, 4) BSTAGE(16, 2) BSTAGE(16, 1)
  BSTAGE(32, 16) BSTAGE(32, 8) BSTAGE(32, 4) BSTAGE(32, 2) BSTAGE(32, 1)
  BSTAGE(64, 32) BSTAGE(64, 16) BSTAGE(64, 8) BSTAGE(64, 4) BSTAGE(64, 2) BSTAGE(64, 1)
#undef BSTAGE
  return key;
}

// W1 [131][256] f32 -> W1T bf16 [256][160]; W2 [256][256] -> W2T [256][256].
// Block 416 zeroes the 1024-double stats block instead.
__global__ void prep_weights(const float* __restrict__ W1, const float* __restrict__ W2,
                             unsigned short* __restrict__ W1T, unsigned short* __restrict__ W2T,
                             double* __restrict__ stats) {
  if (blockIdx.x == 416) {
    for (int i = threadIdx.x; i < 1024; i += 256) stats[i] = 0.0;
    return;
  }
  int i = blockIdx.x * 256 + threadIdx.x;
  if (i < 256 * K1) {
    int n = i / K1, k = i % K1;
    float v = (k < 131) ? W1[k * 256 + n] : 0.f;
    W1T[i] = f2bf(v);
  } else {
    int j = i - 256 * K1;
    if (j < 256 * 256) {
      int n = j / 256, k = j % 256;
      W2T[j] = f2bf(W2[k * 256 + n]);
    }
  }
}

// Exact 16-NN, one wave per query. key = (f32_dist_bits << 11) | idx (unique ->
// lexicographic (d, idx) == jax.lax.top_k tie rule). Pass 1: compute all 32 keys
// per lane into REGISTERS, track per-lane min. Tkey = 16th smallest of the 64
// lane minima (safe bound; <= 481 survivors). Pass 2: ballot-compact from regs.
// LDS = 16K(pxy) + 8K(pz) + 16K(sbuf) = 40960 B exactly -> 4 blocks/CU.
__global__ __launch_bounds__(256, 4) void knn_kernel(const float* __restrict__ pos,
                                                     int* __restrict__ nn_idx) {
#pragma clang fp contract(off)
  __shared__ float2 pxy[NPTS];
  __shared__ float pzz[NPTS];
  __shared__ unsigned long long sbuf[4][512];
  const int b = blockIdx.y;
  const int tid = threadIdx.x;
  const float* pb = pos + (size_t)b * NPTS * 3;
  for (int i = tid; i < NPTS; i += 256) {
    pxy[i] = make_float2(pb[3 * i], pb[3 * i + 1]);
    pzz[i] = pb[3 * i + 2];
  }
  __syncthreads();
  const int lane = tid & 63;
  const int wid = tid >> 6;
  const int q = blockIdx.x * 4 + wid;  // query within batch
  const float2 qxy = pxy[q];           // wave-uniform broadcast reads
  const float qz = pzz[q];

  unsigned long long keys[32];
  unsigned long long mink = ~0ull;
#pragma unroll
  for (int t = 0; t < 32; ++t) {
    const int j = lane + (t << 6);
    float2 pp = pxy[j];
    float pz = pzz[j];
    float dx = qxy.x - pp.x;
    float dy = qxy.y - pp.y;
    float dz = qz - pz;
    float d = ((dx * dx) + (dy * dy)) + (dz * dz);  // reference order, no fma
    unsigned long long key = ((unsigned long long)__float_as_uint(d) << 11) | (unsigned)j;
    keys[t] = key;
    mink = (key < mink) ? key : mink;
  }
  unsigned long long skey = bitonic_sort64(mink, lane);
  unsigned Tlo = (unsigned)__builtin_amdgcn_readlane((int)(unsigned)skey, 15);
  unsigned Thi = (unsigned)__builtin_amdgcn_readlane((int)(unsigned)(skey >> 32), 15);
  const unsigned long long Tkey = ((unsigned long long)Thi << 32) | Tlo;

  // Pass 2: compact survivors (key <= Tkey) into per-wave LDS buffer, from regs.
  unsigned long long* buf = sbuf[wid];
  int base = 0;
#pragma unroll
  for (int t = 0; t < 32; ++t) {
    unsigned long long key = keys[t];
    bool surv = key <= Tkey;
    unsigned long long mask = __ballot(surv);
    if (surv) {
      int off = __popcll(mask & ((1ull << lane) - 1ull));
      buf[base + off] = key;
    }
    base += (int)__popcll(mask);
  }

  int* out = nn_idx + ((size_t)b * NPTS + q) * KNNK;
  if (base <= 64) {
    unsigned long long key = (lane < base) ? buf[lane] : ~0ull;
    key = bitonic_sort64(key, lane);
    if (lane < 16) out[lane] = (int)(key & 2047ull);
  } else {
    // rare exact fallback: iterative wave-argmin extraction (base <= 481)
    unsigned long long mk[8];
#pragma unroll
    for (int j2 = 0; j2 < 8; ++j2) {
      int t2 = lane + (j2 << 6);
      mk[j2] = (t2 < base) ? buf[t2] : ~0ull;
    }
    for (int o = 0; o < 16; ++o) {
      unsigned long long m = mk[0];
#pragma unroll
      for (int j2 = 1; j2 < 8; ++j2) m = (mk[j2] < m) ? mk[j2] : m;
#pragma unroll
      for (int off = 32; off > 0; off >>= 1) {
        unsigned long long o2 = shflxor64(m, off);
        m = (o2 < m) ? o2 : m;
      }
      if (lane == 0) out[o] = (int)(m & 2047ull);
#pragma unroll
      for (int j2 = 0; j2 < 8; ++j2) mk[j2] = (mk[j2] == m) ? ~0ull : mk[j2];
    }
  }
}

// One wave per point. Lane handles channels (2*lane, 2*lane+1) via float2
// coalesced reads (512B per neighbor row). Same f32 sum order as before.
__global__ __launch_bounds__(256) void gather_avg(const float* __restrict__ x,
                                                  const float* __restrict__ pos,
                                                  const int* __restrict__ nn_idx,
                                                  unsigned short* __restrict__ avg) {
  const int lane = threadIdx.x & 63;
  const int wid = threadIdx.x >> 6;
  const int p = blockIdx.x * 4 + wid;
  const int b = p >> 11;
  const int* ip = nn_idx + (size_t)p * KNNK;
  int idx[16];
#pragma unroll
  for (int k = 0; k < 16; ++k) idx[k] = ip[k];
  const float* xb = x + (size_t)b * NPTS * CC;
  float ax = 0.f, ay = 0.f;
#pragma unroll
  for (int k = 0; k < 16; ++k) {
    float2 v = *(const float2*)(xb + (size_t)idx[k] * CC + lane * 2);
    ax += v.x;
    ay += v.y;
  }
  unsigned short h0 = f2bf(ax * 0.0625f);
  unsigned short h1 = f2bf(ay * 0.0625f);
  *(unsigned*)(avg + (size_t)p * K1 + lane * 2) = (unsigned)h0 | ((unsigned)h1 << 16);
  if (lane < 32) {
    unsigned short o = 0;
    if (lane < 3) {
      const float* pb = pos + (size_t)b * NPTS * 3;
      float v = 0.f;
#pragma unroll
      for (int k = 0; k < 16; ++k) v += pb[idx[k] * 3 + lane];
      o = f2bf(v * 0.0625f);
    }
    avg[(size_t)p * K1 + 128 + lane] = o;
  }
}

// GEMM + bias; accumulates per-column sum/sumsq into global doubles (block
// partials via shuffle + LDS float atomics, one double atomic per col/block);
// writes pre-activations as bf16. No grid sync.
__global__ __launch_bounds__(256) void gemm_stats(
    const unsigned short* __restrict__ A, const unsigned short* __restrict__ BT,
    const float* __restrict__ bias, double* __restrict__ dsum,
    double* __restrict__ dsumsq, unsigned short* __restrict__ pre, int Kp) {
  __shared__ __align__(16) unsigned short As[64][56];
  __shared__ __align__(16) unsigned short Bs[64][56];
  __shared__ float sSum[64], sSq[64];
  const int tid = threadIdx.x;
  if (tid < 64) { sSum[tid] = 0.f; sSq[tid] = 0.f; }
  const int m0 = blockIdx.x * 64;
  const int n0 = blockIdx.y * 64;
  const int w = tid >> 6, lane = tid & 63;
  const int wr = w >> 1, wc = w & 1;
  const int l15 = lane & 15;
  const int g = lane >> 4;
  const int kk = g * 8;
  f32x4 acc[2][2] = {};
  const int sr = tid >> 2;
  const int sk = (tid & 3) * 8;
  const unsigned short* Aptr = A + (size_t)(m0 + sr) * Kp + sk;
  const unsigned short* Bptr = BT + (size_t)(n0 + sr) * Kp + sk;
  for (int k0 = 0; k0 < Kp; k0 += 32) {
    *(int4*)(&As[sr][sk]) = *(const int4*)(Aptr + k0);
    *(int4*)(&Bs[sr][sk]) = *(const int4*)(Bptr + k0);
    __syncthreads();
    bf16x8 a0  = *(const bf16x8*)(&As[wr * 32 + l15][kk]);
    bf16x8 a1  = *(const bf16x8*)(&As[wr * 32 + 16 + l15][kk]);
    bf16x8 b0  = *(const bf16x8*)(&Bs[wc * 32 + l15][kk]);
    bf16x8 b1v = *(const bf16x8*)(&Bs[wc * 32 + 16 + l15][kk]);
    acc[0][0] = __builtin_amdgcn_mfma_f32_16x16x32_bf16(a0, b0,  acc[0][0], 0, 0, 0);
    acc[0][1] = __builtin_amdgcn_mfma_f32_16x16x32_bf16(a0, b1v, acc[0][1], 0, 0, 0);
    acc[1][0] = __builtin_amdgcn_mfma_f32_16x16x32_bf16(a1, b0,  acc[1][0], 0, 0, 0);
    acc[1][1] = __builtin_amdgcn_mfma_f32_16x16x32_bf16(a1, b1v, acc[1][1], 0, 0, 0);
    __syncthreads();
  }

  float s[2] = {0.f, 0.f}, q2[2] = {0.f, 0.f};
  unsigned short vb[2][2][4];
#pragma unroll
  for (int fc = 0; fc < 2; ++fc) {
    float bv = bias[n0 + wc * 32 + fc * 16 + l15];
#pragma unroll
    for (int fr = 0; fr < 2; ++fr)
#pragma unroll
      for (int r = 0; r < 4; ++r) {
        float xv = acc[fr][fc][r] + bv;
        unsigned short h = f2bf(xv);
        vb[fr][fc][r] = h;
        float xq = bf2f(h);          // stats from the stored bf16 values
        s[fc] += xq;
        q2[fc] = fmaf(xq, xq, q2[fc]);
      }
  }
#pragma unroll
  for (int fc = 0; fc < 2; ++fc) {
    s[fc] += __shfl_xor(s[fc], 16, 64);
    s[fc] += __shfl_xor(s[fc], 32, 64);
    q2[fc] += __shfl_xor(q2[fc], 16, 64);
    q2[fc] += __shfl_xor(q2[fc], 32, 64);
  }
  if (lane < 16) {
#pragma unroll
    for (int fc = 0; fc < 2; ++fc) {
      atomicAdd(&sSum[wc * 32 + fc * 16 + lane], s[fc]);
      atomicAdd(&sSq[wc * 32 + fc * 16 + lane], q2[fc]);
    }
  }
  // write pre-activation bf16 while the LDS reduction settles
#pragma unroll
  for (int fc = 0; fc < 2; ++fc) {
    int col = n0 + wc * 32 + fc * 16 + l15;
#pragma unroll
    for (int fr = 0; fr < 2; ++fr)
#pragma unroll
      for (int r = 0; r < 4; ++r) {
        int row = m0 + wr * 32 + fr * 16 + g * 4 + r;
        pre[(size_t)row * OO + col] = vb[fr][fc][r];
      }
  }
  __syncthreads();
  if (tid < 64) {
    atomicAdd(&dsum[n0 + tid], (double)sSum[tid]);
    atomicAdd(&dsumsq[n0 + tid], (double)sSq[tid]);
  }
}

// Streams pre (bf16 [MM][256]) -> BN(+ReLU). Each block derives scale/shift
// from the global double stats itself (no separate finalize kernel).
template <bool RELU>
__global__ __launch_bounds__(256) void bn_apply(const unsigned short* __restrict__ pre,
                                                const double* __restrict__ dsum,
                                                const double* __restrict__ dsumsq,
                                                const float* __restrict__ gamma,
                                                const float* __restrict__ beta,
                                                void* __restrict__ outp) {
  __shared__ float sSc[256], sSh[256];
  const int tid = threadIdx.x;
  {
    double mu = dsum[tid] * (1.0 / 16384.0);
    double var = dsumsq[tid] * (1.0 / 16384.0) - mu * mu;
    float sc = (float)((double)gamma[tid] / sqrt(var + 1e-5));
    sSc[tid] = sc;
    sSh[tid] = beta[tid] - (float)mu * sc;
  }
  __syncthreads();
  const int cg = (tid & 31) * 8;
  float sc[8], sh[8];
#pragma unroll
  for (int j = 0; j < 8; ++j) { sc[j] = sSc[cg + j]; sh[j] = sSh[cg + j]; }
  const int r0 = blockIdx.x * 32 + (tid >> 5);
#pragma unroll
  for (int it = 0; it < 4; ++it) {
    const int row = r0 + it * 8;
    u16x8 v = *(const u16x8*)(pre + (size_t)row * OO + cg);
    if constexpr (RELU) {
      u16x8 o;
#pragma unroll
      for (int j = 0; j < 8; ++j)
        o[j] = f2bf(fmaxf(fmaf(bf2f(v[j]), sc[j], sh[j]), 0.f));
      *(u16x8*)((unsigned short*)outp + (size_t)row * OO + cg) = o;
    } else {
      float4 o0, o1;
      o0.x = fmaf(bf2f(v[0]), sc[0], sh[0]);
      o0.y = fmaf(bf2f(v[1]), sc[1], sh[1]);
      o0.z = fmaf(bf2f(v[2]), sc[2], sh[2]);
      o0.w = fmaf(bf2f(v[3]), sc[3], sh[3]);
      o1.x = fmaf(bf2f(v[4]), sc[4], sh[4]);
      o1.y = fmaf(bf2f(v[5]), sc[5], sh[5]);
      o1.z = fmaf(bf2f(v[6]), sc[6], sh[6]);
      o1.w = fmaf(bf2f(v[7]), sc[7], sh[7]);
      float* op = (float*)outp + (size_t)row * OO + cg;
      *(float4*)op = o0;
      *(float4*)(op + 4) = o1;
    }
  }
}

}  // namespace

extern "C" void kernel_launch(void* const* d_in, const int* in_sizes, int n_in,
                              void* d_out, int out_size, void* d_ws, size_t ws_size,
                              hipStream_t stream) {
  const float* x   = (const float*)d_in[0];
  const float* pos = (const float*)d_in[1];
  const float* W1  = (const float*)d_in[2];
  const float* b1  = (const float*)d_in[3];
  const float* g1  = (const float*)d_in[4];
  const float* be1 = (const float*)d_in[5];
  const float* W2  = (const float*)d_in[6];
  const float* b2  = (const float*)d_in[7];
  const float* g2  = (const float*)d_in[8];
  const float* be2 = (const float*)d_in[9];

  char* ws = (char*)d_ws;
  double* stats        = (double*)(ws + 0);                  // 1024 doubles
  int* nn_idx          = (int*)(ws + 12288);                 // 16384*16 int
  unsigned short* avg  = (unsigned short*)(ws + 1060864);    // 16384*160 bf16
  unsigned short* W1T  = (unsigned short*)(ws + 6303744);    // 256*160 bf16
  unsigned short* W2T  = (unsigned short*)(ws + 6385664);    // 256*256 bf16
  unsigned short* hbuf = (unsigned short*)(ws + 6516736);    // 16384*256 bf16
  unsigned short* pre1 = (unsigned short*)(ws + 14905344);   // 16384*256 bf16
  unsigned short* pre2 = (unsigned short*)(ws + 23293952);   // 16384*256 bf16

  prep_weights<<<417, 256, 0, stream>>>(W1, W2, W1T, W2T, stats);
  knn_kernel<<<dim3(NPTS / 4, BB), 256, 0, stream>>>(pos, nn_idx);
  gather_avg<<<MM / 4, 256, 0, stream>>>(x, pos, nn_idx, avg);
  gemm_stats<<<dim3(MM / 64, OO / 64), 256, 0, stream>>>(
      avg, W1T, b1, stats, stats + 256, pre1, K1);
  bn_apply<true><<<MM / 32, 256, 0, stream>>>(pre1, stats, stats + 256, g1, be1, hbuf);
  gemm_stats<<<dim3(MM / 64, OO / 64), 256, 0, stream>>>(
      hbuf, W2T, b2, stats + 512, stats + 768, pre2, OO);
  bn_apply<false><<<MM / 32, 256, 0, stream>>>(pre2, stats + 512, stats + 768, g2, be2, d_out);
}